// Round 8
// baseline (802.608 us; speedup 1.0000x reference)
//
#include <hip/hip_runtime.h>
#include <math.h>

// MinVQVAE1D forward. 256x256-tile MFMA GEMMs (128x64 per wave, 2-buffer
// pipelined) with LDS-bounce coalesced epilogues. Split-bf16 encoder+scores,
// plain bf16 decoder. N=16384, D=1024, H=1024, L=256, K=4096.
// out = [x_pred (N*D) f32 | z_discrete 0/1 f32 (N*K) | loss (1)]

#define MB (1024ULL * 1024ULL)

typedef __attribute__((ext_vector_type(8))) short s16x8;
typedef __attribute__((ext_vector_type(4))) float f32x4;

__device__ __forceinline__ ushort f2bf(float f) {
    unsigned u = __float_as_uint(f);
    u += 0x7fffu + ((u >> 16) & 1u);
    return (ushort)(u >> 16);
}
__device__ __forceinline__ float bf2f(ushort h) {
    return __uint_as_float(((unsigned)h) << 16);
}
__device__ __forceinline__ float gelu_f(float v) {
    return 0.5f * v * (1.0f + erff(v * 0.70710678118654752f));
}
__device__ __forceinline__ void gload16(const void* g, void* l) {
    __builtin_amdgcn_global_load_lds(
        (const __attribute__((address_space(1))) void*)g,
        (__attribute__((address_space(3))) void*)l, 16, 0, 0);
}

// ---------------------------------------------------------------------------
// f32 [R][K] -> hilo-packed bf16: row stride 2K ushorts, per 32-k slab:
// [32 hi | 32 lo].
__global__ __launch_bounds__(256)
void split_pack(const float* __restrict__ in, ushort* __restrict__ out,
                int R, int K)
{
    const int nch = R * (K >> 3);
    for (int i = blockIdx.x * 256 + threadIdx.x; i < nch; i += gridDim.x * 256) {
        const int row = i / (K >> 3);
        const int k8 = (i - row * (K >> 3)) * 8;
        const float4 v0 = *(const float4*)(in + (size_t)row * K + k8);
        const float4 v1 = *(const float4*)(in + (size_t)row * K + k8 + 4);
        float f[8] = {v0.x, v0.y, v0.z, v0.w, v1.x, v1.y, v1.z, v1.w};
        ushort h[8], l[8];
        #pragma unroll
        for (int j = 0; j < 8; j++) {
            h[j] = f2bf(f[j]);
            l[j] = f2bf(f[j] - bf2f(h[j]));
        }
        size_t o = (size_t)row * 2 * K + ((k8 >> 5) << 6) + (k8 & 31);
        *(ushort4*)(out + o)      = make_ushort4(h[0], h[1], h[2], h[3]);
        *(ushort4*)(out + o + 4)  = make_ushort4(h[4], h[5], h[6], h[7]);
        *(ushort4*)(out + o + 32) = make_ushort4(l[0], l[1], l[2], l[3]);
        *(ushort4*)(out + o + 36) = make_ushort4(l[4], l[5], l[6], l[7]);
    }
}

// W [Kd, Nn] f32 -> out [Nn][Kd]; PACK -> hilo-packed, else plain bf16.
template<bool PACK>
__global__ __launch_bounds__(256)
void transpose_cvt(const float* __restrict__ in, ushort* __restrict__ out,
                   int Kd, int Nn)
{
    __shared__ float tile[32][33];
    const int n0 = blockIdx.x * 32, k0 = blockIdx.y * 32;
    const int tx = threadIdx.x & 31, ty = threadIdx.x >> 5;
    #pragma unroll
    for (int r = 0; r < 4; r++)
        tile[ty + r * 8][tx] = in[(size_t)(k0 + ty + r * 8) * Nn + n0 + tx];
    __syncthreads();
    #pragma unroll
    for (int r = 0; r < 4; r++) {
        const float v = tile[tx][ty + r * 8];
        const int row = n0 + ty + r * 8, k = k0 + tx;
        if constexpr (PACK) {
            size_t o = (size_t)row * 2 * Kd + ((k >> 5) << 6) + (k & 31);
            ushort h = f2bf(v);
            out[o] = h;
            out[o + 32] = f2bf(v - bf2f(h));
        } else {
            out[(size_t)row * Kd + k] = f2bf(v);
        }
    }
}

// ||e_k||^2 per codebook row (L=256)
__global__ __launch_bounds__(64)
void colnorm(const float* __restrict__ pool, float* __restrict__ c)
{
    int r = blockIdx.x, lane = threadIdx.x;
    float4 v = *(const float4*)(pool + (size_t)r * 256 + lane * 4);
    float s = v.x * v.x + v.y * v.y + v.z * v.z + v.w * v.w;
    #pragma unroll
    for (int o = 32; o > 0; o >>= 1) s += __shfl_down(s, o);
    if (lane == 0) c[r] = s;
}

// ---------------------------------------------------------------------------
// Big MFMA GEMM: C[M,Nn] = A[M,Kd] @ B^T, B given as [Nn,Kd].
// Block tile 256x256, 512 threads = 8 waves (2x4), per-wave 128x64 output.
// 2 LDS buffers x 64KB, depth-1 prefetch: vmcnt(0) -> barrier -> STAGE(t+1)
// -> compute(t). XCD-bijective block swizzle. LDS-bounce coalesced epilogue
// (4 chunks x 64 rows -> contiguous dwordx4 streams).
// SPLIT: BK=32 hilo slab (3 MFMA/frag pair); plain: BK=64.
// EPI: 0=+bias, 1=gelu(+bias), 2=sigmoid(+bias)+SSE, 3=VQ argmin partials.
template<int EPI, bool SPLIT, bool PACKOUT>
__global__ __launch_bounds__(512, 2)
void gemm_big(const ushort* __restrict__ A, const ushort* __restrict__ B,
              const float* __restrict__ bias, int Kd, int Nn,
              int rsA, int rsB,                    // row strides in BYTES
              ushort* __restrict__ Cu, float* __restrict__ Cf,
              const float* __restrict__ xref, float* __restrict__ ssePartial,
              float* __restrict__ pval, int* __restrict__ pidx)
{
    extern __shared__ ushort smem[];
    constexpr int BUFS = 512 * 64;                  // 64KB per buffer

    const int tid = threadIdx.x;
    const int wave = tid >> 6, lane = tid & 63;

    const int nx = gridDim.x;
    const int nwg = nx * gridDim.y;
    const int orig = blockIdx.y * nx + blockIdx.x;
    const int wgid = (orig & 7) * (nwg >> 3) + (orig >> 3);
    const int bx = wgid % nx, by = wgid / nx;

    const int m0 = by * 256, n0 = bx * 256;
    const int wr = wave >> 2, wc = wave & 3;        // 2 x 4 wave grid
    const int fcol = lane & 15, kgrp = lane >> 4;
    const int NT = Kd / (SPLIT ? 32 : 64);

    const int srow = lane >> 3;                     // row within 8-row chunk
    const int sswz = ((lane & 7) ^ srow) << 4;      // swizzled src byte
    const char* Abase = (const char*)A + (size_t)m0 * rsA;
    const char* Bbase = (const char*)B + (size_t)n0 * rsB;

    f32x4 acc[8][4];
    #pragma unroll
    for (int m = 0; m < 8; m++)
        #pragma unroll
        for (int n = 0; n < 4; n++)
            acc[m][n] = (f32x4){0.f, 0.f, 0.f, 0.f};

    auto STAGE = [&](int buf, int t) {
        ushort* dst = smem + buf * BUFS;
        const size_t kb = (size_t)t * 128;
        #pragma unroll
        for (int g = 0; g < 4; g++) {
            const int rb = g * 64 + wave * 8;
            gload16(Abase + (size_t)(rb + srow) * rsA + kb + sswz, dst + rb * 64);
            gload16(Bbase + (size_t)(rb + srow) * rsB + kb + sswz,
                    dst + (256 + rb) * 64);
        }
    };
    auto LD = [&](int buf, int r, int u) -> s16x8 {
        return *(const s16x8*)(smem + buf * BUFS + r * 64 + ((u ^ (r & 7)) << 3));
    };

    STAGE(0, 0);
    for (int t = 0; t < NT; ++t) {
        asm volatile("s_waitcnt vmcnt(0)" ::: "memory");
        __builtin_amdgcn_s_barrier();
        if (t + 1 < NT) STAGE((t + 1) & 1, t + 1);
        const int buf = t & 1;
        if constexpr (SPLIT) {
            s16x8 bH[4], bL[4];
            #pragma unroll
            for (int n = 0; n < 4; n++) {
                const int r = 256 + wc * 64 + n * 16 + fcol;
                bH[n] = LD(buf, r, kgrp);
                bL[n] = LD(buf, r, 4 + kgrp);
            }
            #pragma unroll
            for (int h = 0; h < 2; h++) {
                s16x8 aH[4], aL[4];
                #pragma unroll
                for (int i = 0; i < 4; i++) {
                    const int r = wr * 128 + (h * 4 + i) * 16 + fcol;
                    aH[i] = LD(buf, r, kgrp);
                    aL[i] = LD(buf, r, 4 + kgrp);
                }
                __builtin_amdgcn_s_setprio(1);
                #pragma unroll
                for (int i = 0; i < 4; i++)
                    #pragma unroll
                    for (int n = 0; n < 4; n++) {
                        acc[h * 4 + i][n] = __builtin_amdgcn_mfma_f32_16x16x32_bf16(
                            aH[i], bH[n], acc[h * 4 + i][n], 0, 0, 0);
                        acc[h * 4 + i][n] = __builtin_amdgcn_mfma_f32_16x16x32_bf16(
                            aH[i], bL[n], acc[h * 4 + i][n], 0, 0, 0);
                        acc[h * 4 + i][n] = __builtin_amdgcn_mfma_f32_16x16x32_bf16(
                            aL[i], bH[n], acc[h * 4 + i][n], 0, 0, 0);
                    }
                __builtin_amdgcn_s_setprio(0);
            }
        } else {
            s16x8 b2[4][2];
            #pragma unroll
            for (int n = 0; n < 4; n++) {
                const int r = 256 + wc * 64 + n * 16 + fcol;
                #pragma unroll
                for (int ks = 0; ks < 2; ks++) b2[n][ks] = LD(buf, r, ks * 4 + kgrp);
            }
            #pragma unroll
            for (int h = 0; h < 2; h++) {
                s16x8 a2[4][2];
                #pragma unroll
                for (int i = 0; i < 4; i++) {
                    const int r = wr * 128 + (h * 4 + i) * 16 + fcol;
                    #pragma unroll
                    for (int ks = 0; ks < 2; ks++) a2[i][ks] = LD(buf, r, ks * 4 + kgrp);
                }
                __builtin_amdgcn_s_setprio(1);
                #pragma unroll
                for (int i = 0; i < 4; i++)
                    #pragma unroll
                    for (int n = 0; n < 4; n++)
                        #pragma unroll
                        for (int ks = 0; ks < 2; ks++)
                            acc[h * 4 + i][n] = __builtin_amdgcn_mfma_f32_16x16x32_bf16(
                                a2[i][ks], b2[n][ks], acc[h * 4 + i][n], 0, 0, 0);
                __builtin_amdgcn_s_setprio(0);
            }
        }
    }
    __builtin_amdgcn_sched_barrier(0);
    __syncthreads();                               // retire LDS reads; reuse smem

    // ------------------------------ epilogue ------------------------------
    int colg[4];
    float bcol[4];
    #pragma unroll
    for (int n = 0; n < 4; n++) {
        colg[n] = n0 + wc * 64 + n * 16 + fcol;
        bcol[n] = bias[colg[n]];
    }

    if constexpr (EPI == 0 || EPI == 1) {
        // LDS-bounce: 4 chunks of 64 rows; coalesced dwordx4 streams out.
        ushort* LB = smem;
        constexpr int SJ = PACKOUT ? 520 : 264;
        #pragma unroll
        for (int c = 0; c < 4; c++) {
            if (wr == (c >> 1)) {
                #pragma unroll
                for (int m2 = 0; m2 < 4; m2++) {
                    const int m = (c & 1) * 4 + m2;
                    #pragma unroll
                    for (int v = 0; v < 4; v++) {
                        const int lrow = m2 * 16 + kgrp * 4 + v;
                        #pragma unroll
                        for (int n = 0; n < 4; n++) {
                            float val = acc[m][n][v] + bcol[n];
                            if (EPI == 1) val = gelu_f(val);
                            const int cl = wc * 64 + n * 16 + fcol;
                            if constexpr (PACKOUT) {
                                const int off = ((cl >> 5) << 6) + (cl & 31);
                                ushort h = f2bf(val);
                                LB[lrow * SJ + off] = h;
                                LB[lrow * SJ + off + 32] = f2bf(val - bf2f(h));
                            } else {
                                LB[lrow * SJ + cl] = f2bf(val);
                            }
                        }
                    }
                }
            }
            __syncthreads();
            const int lrow = tid >> 3, seg = tid & 7;
            const int row_g = m0 + c * 64 + lrow;
            if constexpr (PACKOUT) {
                ushort* gp = Cu + (size_t)row_g * 2 * Nn + n0 * 2 + seg * 64;
                #pragma unroll
                for (int j = 0; j < 8; j++)
                    *(s16x8*)(gp + j * 8) =
                        *(const s16x8*)(LB + lrow * SJ + seg * 64 + j * 8);
            } else {
                ushort* gp = Cu + (size_t)row_g * Nn + n0 + seg * 32;
                #pragma unroll
                for (int j = 0; j < 4; j++)
                    *(s16x8*)(gp + j * 8) =
                        *(const s16x8*)(LB + lrow * SJ + seg * 32 + j * 8);
            }
            __syncthreads();
        }
    } else if constexpr (EPI == 2) {
        float* LF = (float*)smem;
        constexpr int SJ = 260;
        float lsse = 0.0f;
        #pragma unroll
        for (int c = 0; c < 4; c++) {
            if (wr == (c >> 1)) {
                #pragma unroll
                for (int m2 = 0; m2 < 4; m2++) {
                    const int m = (c & 1) * 4 + m2;
                    #pragma unroll
                    for (int v = 0; v < 4; v++) {
                        const int lrow = m2 * 16 + kgrp * 4 + v;
                        #pragma unroll
                        for (int n = 0; n < 4; n++) {
                            float val = acc[m][n][v] + bcol[n];
                            val = 1.0f / (1.0f + expf(-val));
                            LF[lrow * SJ + wc * 64 + n * 16 + fcol] = val;
                        }
                    }
                }
            }
            __syncthreads();
            const int lrow = tid >> 3, seg = tid & 7;
            const int row_g = m0 + c * 64 + lrow;
            const size_t rb = (size_t)row_g * Nn + n0 + seg * 32;
            #pragma unroll
            for (int j = 0; j < 8; j++) {
                f32x4 v4 = *(const f32x4*)(LF + lrow * SJ + seg * 32 + j * 4);
                const float4 xr = *(const float4*)(xref + rb + j * 4);
                __builtin_nontemporal_store(v4, (f32x4*)(Cf + rb + j * 4));
                float d0 = xr.x - v4[0], d1 = xr.y - v4[1];
                float d2 = xr.z - v4[2], d3 = xr.w - v4[3];
                lsse += d0 * d0 + d1 * d1 + d2 * d2 + d3 * d3;
            }
            __syncthreads();
        }
        float* red = (float*)smem;
        red[tid] = lsse;
        __syncthreads();
        for (int s = 256; s > 0; s >>= 1) {
            if (tid < s) red[tid] += red[tid + s];
            __syncthreads();
        }
        if (tid == 0) ssePartial[by * nx + bx] = red[0];
    } else if constexpr (EPI == 3) {
        float* sv = (float*)smem;            // [4][256]
        int*   si = (int*)(sv + 1024);
        #pragma unroll
        for (int m = 0; m < 8; m++)
            #pragma unroll
            for (int v = 0; v < 4; v++) {
                float best = INFINITY;
                int bidx = 0x7fffffff;
                #pragma unroll
                for (int n = 0; n < 4; n++) {
                    float sc = bcol[n] - 2.0f * acc[m][n][v];
                    if (sc < best || (sc == best && colg[n] < bidx)) { best = sc; bidx = colg[n]; }
                }
                #pragma unroll
                for (int d = 1; d < 16; d <<= 1) {
                    float ov = __shfl_xor(best, d, 64);
                    int   oi = __shfl_xor(bidx, d, 64);
                    if (ov < best || (ov == best && oi < bidx)) { best = ov; bidx = oi; }
                }
                if (fcol == 0) {
                    const int rl = wr * 128 + m * 16 + kgrp * 4 + v;
                    sv[wc * 256 + rl] = best;
                    si[wc * 256 + rl] = bidx;
                }
            }
        __syncthreads();
        if (tid < 256) {
            float v0 = sv[tid];
            int   i0 = si[tid];
            #pragma unroll
            for (int c = 1; c < 4; c++) {
                float v1 = sv[c * 256 + tid];
                int   i1 = si[c * 256 + tid];
                if (v1 < v0 || (v1 == v0 && i1 < i0)) { v0 = v1; i0 = i1; }
            }
            pval[(size_t)(m0 + tid) * nx + bx] = v0;
            pidx[(size_t)(m0 + tid) * nx + bx] = i0;
        }
    }
}

// ---------------------------------------------------------------------------
// enc3 GEMM: 128x128 tile, waves 2x4 (64x32/wave), 3 buffers, distance-2
// prefetch, counted vmcnt(4). SPLIT, PACKOUT, LDS-bounce epilogue.
__global__ __launch_bounds__(512, 2)
void gemm_enc3(const ushort* __restrict__ A, const ushort* __restrict__ B,
               const float* __restrict__ bias, int Kd, int Nn,
               int rsA, int rsB, ushort* __restrict__ Cu)
{
    extern __shared__ ushort smem[];
    constexpr int BUFS = 256 * 64;                  // 32KB per buffer

    const int tid = threadIdx.x;
    const int wave = tid >> 6, lane = tid & 63;

    const int nx = gridDim.x;
    const int nwg = nx * gridDim.y;
    const int orig = blockIdx.y * nx + blockIdx.x;
    const int wgid = (orig & 7) * (nwg >> 3) + (orig >> 3);
    const int bx = wgid % nx, by = wgid / nx;

    const int m0 = by * 128, n0 = bx * 128;
    const int wr = wave >> 2, wc = wave & 3;
    const int fcol = lane & 15, kgrp = lane >> 4;
    const int NT = Kd / 32;

    const int srow = lane >> 3;
    const int sswz = ((lane & 7) ^ srow) << 4;
    const char* Abase = (const char*)A + (size_t)m0 * rsA;
    const char* Bbase = (const char*)B + (size_t)n0 * rsB;

    f32x4 acc[4][2];
    #pragma unroll
    for (int m = 0; m < 4; m++)
        #pragma unroll
        for (int n = 0; n < 2; n++)
            acc[m][n] = (f32x4){0.f, 0.f, 0.f, 0.f};

    auto STAGE = [&](int buf, int t) {
        ushort* dst = smem + buf * BUFS;
        const size_t kb = (size_t)t * 128;
        #pragma unroll
        for (int g = 0; g < 2; g++) {
            const int rb = g * 64 + wave * 8;
            gload16(Abase + (size_t)(rb + srow) * rsA + kb + sswz, dst + rb * 64);
            gload16(Bbase + (size_t)(rb + srow) * rsB + kb + sswz,
                    dst + (128 + rb) * 64);
        }
    };
    auto LD = [&](int buf, int r, int u) -> s16x8 {
        return *(const s16x8*)(smem + buf * BUFS + r * 64 + ((u ^ (r & 7)) << 3));
    };

    STAGE(0, 0);
    STAGE(1, 1);
    for (int t = 0; t < NT; ++t) {
        if (t + 1 < NT) asm volatile("s_waitcnt vmcnt(4)" ::: "memory");
        else            asm volatile("s_waitcnt vmcnt(0)" ::: "memory");
        __builtin_amdgcn_s_barrier();
        if (t + 2 < NT) STAGE((t + 2) % 3, t + 2);
        const int buf = t % 3;
        s16x8 aH[4], aL[4], bH[2], bL[2];
        #pragma unroll
        for (int m = 0; m < 4; m++) {
            const int r = wr * 64 + m * 16 + fcol;
            aH[m] = LD(buf, r, kgrp);
            aL[m] = LD(buf, r, 4 + kgrp);
        }
        #pragma unroll
        for (int n = 0; n < 2; n++) {
            const int r = 128 + wc * 32 + n * 16 + fcol;
            bH[n] = LD(buf, r, kgrp);
            bL[n] = LD(buf, r, 4 + kgrp);
        }
        __builtin_amdgcn_s_setprio(1);
        #pragma unroll
        for (int m = 0; m < 4; m++)
            #pragma unroll
            for (int n = 0; n < 2; n++) {
                acc[m][n] = __builtin_amdgcn_mfma_f32_16x16x32_bf16(aH[m], bH[n], acc[m][n], 0, 0, 0);
                acc[m][n] = __builtin_amdgcn_mfma_f32_16x16x32_bf16(aH[m], bL[n], acc[m][n], 0, 0, 0);
                acc[m][n] = __builtin_amdgcn_mfma_f32_16x16x32_bf16(aL[m], bH[n], acc[m][n], 0, 0, 0);
            }
        __builtin_amdgcn_s_setprio(0);
    }
    __builtin_amdgcn_sched_barrier(0);
    __syncthreads();

    // LDS-bounce packed epilogue: 2 chunks of 64 rows.
    ushort* LB = smem;
    constexpr int SJ = 264;
    #pragma unroll
    for (int c = 0; c < 2; c++) {
        if (wr == c) {
            #pragma unroll
            for (int m = 0; m < 4; m++)
                #pragma unroll
                for (int v = 0; v < 4; v++) {
                    const int lrow = m * 16 + kgrp * 4 + v;
                    #pragma unroll
                    for (int n = 0; n < 2; n++) {
                        const int cl = wc * 32 + n * 16 + fcol;
                        const int off = ((cl >> 5) << 6) + (cl & 31);
                        float val = acc[m][n][v] + bias[n0 + cl];
                        ushort h = f2bf(val);
                        LB[lrow * SJ + off] = h;
                        LB[lrow * SJ + off + 32] = f2bf(val - bf2f(h));
                    }
                }
        }
        __syncthreads();
        const int lrow = tid >> 3, seg = tid & 7;
        const int row_g = m0 + c * 64 + lrow;
        ushort* gp = Cu + (size_t)row_g * 2 * Nn + n0 * 2 + seg * 32;
        #pragma unroll
        for (int j = 0; j < 4; j++)
            *(s16x8*)(gp + j * 8) = *(const s16x8*)(LB + lrow * SJ + seg * 32 + j * 8);
        __syncthreads();
    }
}

// ---------------------------------------------------------------------------
// 4 rows per block: reduce nblk block partials -> kbest; one-hot (nontemporal);
// gather z_q; VQ partial.
__global__ __launch_bounds__(256)
void argmin_final(const float* __restrict__ pval, const int* __restrict__ pidx,
                  int nblk, const ushort* __restrict__ zEp,
                  const float* __restrict__ pool,
                  float* __restrict__ zdisc, ushort* __restrict__ zq,
                  float* __restrict__ vqP)
{
    const int t = threadIdx.x;
    const int r = blockIdx.x * 4 + (t >> 6);
    const int l = t & 63;

    float best = INFINITY;
    int bi = 0x7fffffff;
    if (l < nblk) {
        best = pval[(size_t)r * nblk + l];
        bi = pidx[(size_t)r * nblk + l];
    }
    #pragma unroll
    for (int d = 32; d > 0; d >>= 1) {
        float ov = __shfl_xor(best, d, 64);
        int   oi = __shfl_xor(bi, d, 64);
        if (ov < best || (ov == best && oi < bi)) { best = ov; bi = oi; }
    }
    const int kbest = bi;

    f32x4* zrow = (f32x4*)(zdisc + (size_t)r * 4096);
    #pragma unroll
    for (int it = 0; it < 16; it++) {
        const int j = it * 64 + l;
        f32x4 o = (f32x4){0.f, 0.f, 0.f, 0.f};
        if ((kbest >> 2) == j) o[kbest & 3] = 1.0f;
        __builtin_nontemporal_store(o, &zrow[j]);
    }

    const float4 pz = *(const float4*)(pool + (size_t)kbest * 256 + l * 4);
    *(ushort4*)(zq + (size_t)r * 256 + l * 4) =
        make_ushort4(f2bf(pz.x), f2bf(pz.y), f2bf(pz.z), f2bf(pz.w));
    const size_t zo = (size_t)r * 512 + (((l * 4) >> 5) << 6) + ((l * 4) & 31);
    const ushort4 zh = *(const ushort4*)(zEp + zo);
    const ushort4 zl = *(const ushort4*)(zEp + zo + 32);
    float d0 = bf2f(zh.x) + bf2f(zl.x) - pz.x;
    float d1 = bf2f(zh.y) + bf2f(zl.y) - pz.y;
    float d2 = bf2f(zh.z) + bf2f(zl.z) - pz.z;
    float d3 = bf2f(zh.w) + bf2f(zl.w) - pz.w;
    float s = d0 * d0 + d1 * d1 + d2 * d2 + d3 * d3;
    #pragma unroll
    for (int o = 32; o > 0; o >>= 1) s += __shfl_xor(s, o, 64);
    if (l == 0) vqP[r] = s;
}

__global__ __launch_bounds__(256)
void loss_final(const float* __restrict__ sseP, int nP,
                const float* __restrict__ vqP, int nV,
                float* __restrict__ out)
{
    int tid = threadIdx.x;
    float sx = 0.0f, svq = 0.0f;
    for (int i = tid; i < nP; i += 256) sx += sseP[i];
    for (int i = tid; i < nV; i += 256) svq += vqP[i];
    __shared__ float a[256], b[256];
    a[tid] = sx; b[tid] = svq;
    __syncthreads();
    for (int s = 128; s > 0; s >>= 1) {
        if (tid < s) { a[tid] += a[tid + s]; b[tid] += b[tid + s]; }
        __syncthreads();
    }
    if (tid == 0) out[0] = (a[0] + 1.25f * b[0]) / 16384.0f;
}

// ---------------------------------------------------------------------------
extern "C" void kernel_launch(void* const* d_in, const int* in_sizes, int n_in,
                              void* d_out, int out_size, void* d_ws, size_t ws_size,
                              hipStream_t stream)
{
    const float* x    = (const float*)d_in[0];
    const float* pool = (const float*)d_in[1];
    const float* ew1  = (const float*)d_in[2];
    const float* eb1  = (const float*)d_in[3];
    const float* ew2  = (const float*)d_in[4];
    const float* eb2  = (const float*)d_in[5];
    const float* ew3  = (const float*)d_in[6];
    const float* eb3  = (const float*)d_in[7];
    const float* dw1  = (const float*)d_in[8];
    const float* db1  = (const float*)d_in[9];
    const float* dw2  = (const float*)d_in[10];
    const float* db2  = (const float*)d_in[11];
    const float* dw3  = (const float*)d_in[12];
    const float* db3  = (const float*)d_in[13];

    const int N = 16384, D = 1024, H = 1024, L = 256, K = 4096;

    float* out   = (float*)d_out;
    float* xpred = out;
    float* zdisc = out + (size_t)N * D;
    float* lossp = zdisc + (size_t)N * K;

    char* ws = (char*)d_ws;
    ushort* xp    = (ushort*)(ws + 0 * MB);    // 64MB packed x
    ushort* h1p   = (ushort*)(ws + 64 * MB);   // 64MB
    ushort* h2p   = (ushort*)(ws + 128 * MB);  // 64MB
    ushort* zEp   = (ushort*)(ws + 192 * MB);  // 16MB
    ushort* zq    = (ushort*)(ws + 208 * MB);  // 8MB plain bf16
    ushort* poolp = (ushort*)(ws + 216 * MB);  // 4MB
    ushort* w1p   = (ushort*)(ws + 220 * MB);  // 4MB
    ushort* w2p   = (ushort*)(ws + 224 * MB);  // 4MB
    ushort* w3p   = (ushort*)(ws + 228 * MB);  // 1MB
    ushort* v1    = (ushort*)(ws + 229 * MB);  // 0.5MB plain
    ushort* v2    = (ushort*)(ws + 230 * MB);  // 2MB
    ushort* v3    = (ushort*)(ws + 232 * MB);  // 2MB
    ushort* h3    = (ushort*)(ws + 240 * MB);  // 32MB plain
    ushort* h4    = (ushort*)(ws + 272 * MB);  // 32MB
    float*  cn    = (float*)(ws + 304 * MB);   // 16KB
    float*  pv    = (float*)(ws + 305 * MB);   // 1MB
    int*    pi    = (int*)(ws + 307 * MB);     // 1MB
    float*  vqP   = (float*)(ws + 309 * MB);   // 64KB
    float*  sxP   = (float*)(ws + 310 * MB);   // 4KB

    const int SH_BIG = 2 * (512 * 64) * 2;     // 131072 B
    const int SH_E3  = 3 * (256 * 64) * 2;     // 98304 B
    (void)hipFuncSetAttribute((const void*)gemm_big<1, true, true>,
        hipFuncAttributeMaxDynamicSharedMemorySize, SH_BIG);
    (void)hipFuncSetAttribute((const void*)gemm_big<3, true, false>,
        hipFuncAttributeMaxDynamicSharedMemorySize, SH_BIG);
    (void)hipFuncSetAttribute((const void*)gemm_big<1, false, false>,
        hipFuncAttributeMaxDynamicSharedMemorySize, SH_BIG);
    (void)hipFuncSetAttribute((const void*)gemm_big<2, false, false>,
        hipFuncAttributeMaxDynamicSharedMemorySize, SH_BIG);
    (void)hipFuncSetAttribute((const void*)gemm_enc3,
        hipFuncAttributeMaxDynamicSharedMemorySize, SH_E3);

    dim3 blk(256), gblk(512);

    // prep
    split_pack<<<2048, blk, 0, stream>>>(x, xp, N, D);
    split_pack<<<512, blk, 0, stream>>>(pool, poolp, K, L);
    colnorm<<<K, 64, 0, stream>>>(pool, cn);
    transpose_cvt<true><<<dim3(H / 32, D / 32), blk, 0, stream>>>(ew1, w1p, D, H);
    transpose_cvt<true><<<dim3(H / 32, H / 32), blk, 0, stream>>>(ew2, w2p, H, H);
    transpose_cvt<true><<<dim3(L / 32, H / 32), blk, 0, stream>>>(ew3, w3p, H, L);
    transpose_cvt<false><<<dim3(H / 32, L / 32), blk, 0, stream>>>(dw1, v1, L, H);
    transpose_cvt<false><<<dim3(H / 32, H / 32), blk, 0, stream>>>(dw2, v2, H, H);
    transpose_cvt<false><<<dim3(D / 32, H / 32), blk, 0, stream>>>(dw3, v3, H, D);

    // encoder (split, packed in/out)
    gemm_big<1, true, true><<<dim3(H / 256, N / 256), gblk, SH_BIG, stream>>>(
        xp, w1p, eb1, D, H, 2 * D * 2, 2 * D * 2, h1p, nullptr, nullptr, nullptr, nullptr, nullptr);
    gemm_big<1, true, true><<<dim3(H / 256, N / 256), gblk, SH_BIG, stream>>>(
        h1p, w2p, eb2, H, H, 2 * H * 2, 2 * H * 2, h2p, nullptr, nullptr, nullptr, nullptr, nullptr);
    // enc3: 128-tile kernel -> 256 blocks (full GPU; L=256 cols only)
    gemm_enc3<<<dim3(L / 128, N / 128), gblk, SH_E3, stream>>>(
        h2p, w3p, eb3, H, L, 2 * H * 2, 2 * H * 2, zEp);

    // VQ scores + fused per-block argmin (split)
    gemm_big<3, true, false><<<dim3(K / 256, N / 256), gblk, SH_BIG, stream>>>(
        zEp, poolp, cn, L, K, 2 * L * 2, 2 * L * 2, nullptr, nullptr, nullptr, nullptr, pv, pi);

    argmin_final<<<N / 4, blk, 0, stream>>>(pv, pi, K / 256, zEp, pool, zdisc, zq, vqP);

    // decoder (plain bf16)
    gemm_big<1, false, false><<<dim3(H / 256, N / 256), gblk, SH_BIG, stream>>>(
        zq, v1, db1, L, H, L * 2, L * 2, h3, nullptr, nullptr, nullptr, nullptr, nullptr);
    gemm_big<1, false, false><<<dim3(H / 256, N / 256), gblk, SH_BIG, stream>>>(
        h3, v2, db2, H, H, H * 2, H * 2, h4, nullptr, nullptr, nullptr, nullptr, nullptr);
    gemm_big<2, false, false><<<dim3(D / 256, N / 256), gblk, SH_BIG, stream>>>(
        h4, v3, db3, H, D, H * 2, H * 2, nullptr, xpred, x, sxP, nullptr, nullptr);

    loss_final<<<1, blk, 0, stream>>>(sxP, (D / 256) * (N / 256), vqP, N, lossp);
}

// Round 9
// 706.503 us; speedup vs baseline: 1.1360x; 1.1360x over previous
//
#include <hip/hip_runtime.h>
#include <math.h>

// MinVQVAE1D forward. 256x256-tile MFMA GEMMs, 32x32x16 MFMA (2495 TF ceiling
// vs 2176 for 16x16x32), 128x64 per wave, 2-buffer pipelined, r7 scatter
// epilogues. Split-bf16 encoder+scores, plain bf16 decoder.
// N=16384, D=1024, H=1024, L=256, K=4096.
// out = [x_pred (N*D) f32 | z_discrete 0/1 f32 (N*K) | loss (1)]

#define MB (1024ULL * 1024ULL)

typedef __attribute__((ext_vector_type(8))) short s16x8;
typedef __attribute__((ext_vector_type(4))) float f32x4;
typedef __attribute__((ext_vector_type(16))) float f32x16;

__device__ __forceinline__ ushort f2bf(float f) {
    unsigned u = __float_as_uint(f);
    u += 0x7fffu + ((u >> 16) & 1u);
    return (ushort)(u >> 16);
}
__device__ __forceinline__ float bf2f(ushort h) {
    return __uint_as_float(((unsigned)h) << 16);
}
__device__ __forceinline__ float gelu_f(float v) {
    return 0.5f * v * (1.0f + erff(v * 0.70710678118654752f));
}
__device__ __forceinline__ void gload16(const void* g, void* l) {
    __builtin_amdgcn_global_load_lds(
        (const __attribute__((address_space(1))) void*)g,
        (__attribute__((address_space(3))) void*)l, 16, 0, 0);
}

// ---------------------------------------------------------------------------
// f32 [R][K] -> hilo-packed bf16: row stride 2K ushorts, per 32-k slab:
// [32 hi | 32 lo].
__global__ __launch_bounds__(256)
void split_pack(const float* __restrict__ in, ushort* __restrict__ out,
                int R, int K)
{
    const int nch = R * (K >> 3);
    for (int i = blockIdx.x * 256 + threadIdx.x; i < nch; i += gridDim.x * 256) {
        const int row = i / (K >> 3);
        const int k8 = (i - row * (K >> 3)) * 8;
        const float4 v0 = *(const float4*)(in + (size_t)row * K + k8);
        const float4 v1 = *(const float4*)(in + (size_t)row * K + k8 + 4);
        float f[8] = {v0.x, v0.y, v0.z, v0.w, v1.x, v1.y, v1.z, v1.w};
        ushort h[8], l[8];
        #pragma unroll
        for (int j = 0; j < 8; j++) {
            h[j] = f2bf(f[j]);
            l[j] = f2bf(f[j] - bf2f(h[j]));
        }
        size_t o = (size_t)row * 2 * K + ((k8 >> 5) << 6) + (k8 & 31);
        *(ushort4*)(out + o)      = make_ushort4(h[0], h[1], h[2], h[3]);
        *(ushort4*)(out + o + 4)  = make_ushort4(h[4], h[5], h[6], h[7]);
        *(ushort4*)(out + o + 32) = make_ushort4(l[0], l[1], l[2], l[3]);
        *(ushort4*)(out + o + 36) = make_ushort4(l[4], l[5], l[6], l[7]);
    }
}

// W [Kd, Nn] f32 -> out [Nn][Kd]; PACK -> hilo-packed, else plain bf16.
template<bool PACK>
__global__ __launch_bounds__(256)
void transpose_cvt(const float* __restrict__ in, ushort* __restrict__ out,
                   int Kd, int Nn)
{
    __shared__ float tile[32][33];
    const int n0 = blockIdx.x * 32, k0 = blockIdx.y * 32;
    const int tx = threadIdx.x & 31, ty = threadIdx.x >> 5;
    #pragma unroll
    for (int r = 0; r < 4; r++)
        tile[ty + r * 8][tx] = in[(size_t)(k0 + ty + r * 8) * Nn + n0 + tx];
    __syncthreads();
    #pragma unroll
    for (int r = 0; r < 4; r++) {
        const float v = tile[tx][ty + r * 8];
        const int row = n0 + ty + r * 8, k = k0 + tx;
        if constexpr (PACK) {
            size_t o = (size_t)row * 2 * Kd + ((k >> 5) << 6) + (k & 31);
            ushort h = f2bf(v);
            out[o] = h;
            out[o + 32] = f2bf(v - bf2f(h));
        } else {
            out[(size_t)row * Kd + k] = f2bf(v);
        }
    }
}

// ||e_k||^2 per codebook row (L=256)
__global__ __launch_bounds__(64)
void colnorm(const float* __restrict__ pool, float* __restrict__ c)
{
    int r = blockIdx.x, lane = threadIdx.x;
    float4 v = *(const float4*)(pool + (size_t)r * 256 + lane * 4);
    float s = v.x * v.x + v.y * v.y + v.z * v.z + v.w * v.w;
    #pragma unroll
    for (int o = 32; o > 0; o >>= 1) s += __shfl_down(s, o);
    if (lane == 0) c[r] = s;
}

// ---------------------------------------------------------------------------
// Big MFMA GEMM: C[M,Nn] = A[M,Kd] @ B^T, B given as [Nn,Kd].
// Block tile 256x256, 512 threads = 8 waves (2x4), per-wave 128x64 output as
// 4x2 tiles of 32x32 (mfma_f32_32x32x16_bf16). 2 LDS buffers x 64KB, depth-1
// prefetch: vmcnt(0) -> barrier -> STAGE(t+1) -> compute(t). XCD-bijective
// block swizzle. C/D layout: col=lane&31, row=(reg&3)+8*(reg>>2)+4*(lane>>5).
// SPLIT: BK=32 hilo slab (3 MFMA/term pair); plain: BK=64.
// EPI: 0=+bias, 1=gelu(+bias), 2=sigmoid(+bias)+SSE, 3=VQ argmin partials.
template<int EPI, bool SPLIT, bool PACKOUT>
__global__ __launch_bounds__(512, 2)
void gemm_big(const ushort* __restrict__ A, const ushort* __restrict__ B,
              const float* __restrict__ bias, int Kd, int Nn,
              int rsA, int rsB,                    // row strides in BYTES
              ushort* __restrict__ Cu, float* __restrict__ Cf,
              const float* __restrict__ xref, float* __restrict__ ssePartial,
              float* __restrict__ pval, int* __restrict__ pidx)
{
    extern __shared__ ushort smem[];
    constexpr int BUFS = 512 * 64;                  // 64KB per buffer

    const int tid = threadIdx.x;
    const int wave = tid >> 6, lane = tid & 63;
    const int half = lane >> 5, c32 = lane & 31;

    const int nx = gridDim.x;
    const int nwg = nx * gridDim.y;
    const int orig = blockIdx.y * nx + blockIdx.x;
    const int wgid = (orig & 7) * (nwg >> 3) + (orig >> 3);
    const int bx = wgid % nx, by = wgid / nx;

    const int m0 = by * 256, n0 = bx * 256;
    const int wr = wave >> 2, wc = wave & 3;        // 2 x 4 wave grid
    const int NT = Kd / (SPLIT ? 32 : 64);

    const int srow = lane >> 3;                     // row within 8-row chunk
    const int sswz = ((lane & 7) ^ srow) << 4;      // swizzled src byte
    const char* Abase = (const char*)A + (size_t)m0 * rsA;
    const char* Bbase = (const char*)B + (size_t)n0 * rsB;

    f32x16 acc[4][2];
    #pragma unroll
    for (int m = 0; m < 4; m++)
        #pragma unroll
        for (int n = 0; n < 2; n++)
            #pragma unroll
            for (int r = 0; r < 16; r++) acc[m][n][r] = 0.0f;

    auto STAGE = [&](int buf, int t) {
        ushort* dst = smem + buf * BUFS;
        const size_t kb = (size_t)t * 128;
        #pragma unroll
        for (int g = 0; g < 4; g++) {
            const int rb = g * 64 + wave * 8;
            gload16(Abase + (size_t)(rb + srow) * rsA + kb + sswz, dst + rb * 64);
            gload16(Bbase + (size_t)(rb + srow) * rsB + kb + sswz,
                    dst + (256 + rb) * 64);
        }
    };
    auto LD = [&](int buf, int r, int u) -> s16x8 {
        return *(const s16x8*)(smem + buf * BUFS + r * 64 + ((u ^ (r & 7)) << 3));
    };

    STAGE(0, 0);
    for (int t = 0; t < NT; ++t) {
        asm volatile("s_waitcnt vmcnt(0)" ::: "memory");
        __builtin_amdgcn_s_barrier();
        if (t + 1 < NT) STAGE((t + 1) & 1, t + 1);
        const int buf = t & 1;
        if constexpr (SPLIT) {
            s16x8 bH[2][2], bL[2][2];
            #pragma unroll
            for (int n = 0; n < 2; n++) {
                const int r = 256 + wc * 64 + n * 32 + c32;
                #pragma unroll
                for (int kh = 0; kh < 2; kh++) {
                    bH[n][kh] = LD(buf, r, kh * 2 + half);
                    bL[n][kh] = LD(buf, r, 4 + kh * 2 + half);
                }
            }
            #pragma unroll
            for (int mt = 0; mt < 4; mt++) {
                const int r = wr * 128 + mt * 32 + c32;
                s16x8 aH[2], aL[2];
                #pragma unroll
                for (int kh = 0; kh < 2; kh++) {
                    aH[kh] = LD(buf, r, kh * 2 + half);
                    aL[kh] = LD(buf, r, 4 + kh * 2 + half);
                }
                __builtin_amdgcn_s_setprio(1);
                #pragma unroll
                for (int n = 0; n < 2; n++)
                    #pragma unroll
                    for (int kh = 0; kh < 2; kh++) {
                        acc[mt][n] = __builtin_amdgcn_mfma_f32_32x32x16_bf16(
                            aH[kh], bH[n][kh], acc[mt][n], 0, 0, 0);
                        acc[mt][n] = __builtin_amdgcn_mfma_f32_32x32x16_bf16(
                            aH[kh], bL[n][kh], acc[mt][n], 0, 0, 0);
                        acc[mt][n] = __builtin_amdgcn_mfma_f32_32x32x16_bf16(
                            aL[kh], bH[n][kh], acc[mt][n], 0, 0, 0);
                    }
                __builtin_amdgcn_s_setprio(0);
            }
        } else {
            s16x8 b2[2][4];
            #pragma unroll
            for (int n = 0; n < 2; n++) {
                const int r = 256 + wc * 64 + n * 32 + c32;
                #pragma unroll
                for (int kh = 0; kh < 4; kh++) b2[n][kh] = LD(buf, r, kh * 2 + half);
            }
            #pragma unroll
            for (int mt = 0; mt < 4; mt++) {
                const int r = wr * 128 + mt * 32 + c32;
                s16x8 a2[4];
                #pragma unroll
                for (int kh = 0; kh < 4; kh++) a2[kh] = LD(buf, r, kh * 2 + half);
                __builtin_amdgcn_s_setprio(1);
                #pragma unroll
                for (int n = 0; n < 2; n++)
                    #pragma unroll
                    for (int kh = 0; kh < 4; kh++)
                        acc[mt][n] = __builtin_amdgcn_mfma_f32_32x32x16_bf16(
                            a2[kh], b2[n][kh], acc[mt][n], 0, 0, 0);
                __builtin_amdgcn_s_setprio(0);
            }
        }
    }
    __builtin_amdgcn_sched_barrier(0);

    // ------------------------------ epilogue (r7 scatter style) -----------
    if constexpr (EPI == 0 || EPI == 1) {
        #pragma unroll
        for (int mt = 0; mt < 4; mt++)
            #pragma unroll
            for (int nt = 0; nt < 2; nt++) {
                const int col = n0 + wc * 64 + nt * 32 + c32;
                const float bc = bias[col];
                #pragma unroll
                for (int reg = 0; reg < 16; reg++) {
                    const int row = m0 + wr * 128 + mt * 32 +
                                    (reg & 3) + 8 * (reg >> 2) + 4 * half;
                    float val = acc[mt][nt][reg] + bc;
                    if (EPI == 1) val = gelu_f(val);
                    if constexpr (PACKOUT) {
                        size_t o = (size_t)row * 2 * Nn + ((col >> 5) << 6) + (col & 31);
                        ushort h = f2bf(val);
                        Cu[o] = h;
                        Cu[o + 32] = f2bf(val - bf2f(h));
                    } else {
                        Cu[(size_t)row * Nn + col] = f2bf(val);
                    }
                }
            }
    } else if constexpr (EPI == 2) {
        float lsse = 0.0f;
        #pragma unroll
        for (int mt = 0; mt < 4; mt++)
            #pragma unroll
            for (int nt = 0; nt < 2; nt++) {
                const int col = n0 + wc * 64 + nt * 32 + c32;
                const float bc = bias[col];
                #pragma unroll
                for (int reg = 0; reg < 16; reg++) {
                    const int row = m0 + wr * 128 + mt * 32 +
                                    (reg & 3) + 8 * (reg >> 2) + 4 * half;
                    float val = acc[mt][nt][reg] + bc;
                    val = 1.0f / (1.0f + expf(-val));
                    const size_t o = (size_t)row * Nn + col;
                    __builtin_nontemporal_store(val, &Cf[o]);
                    float d = xref[o] - val;
                    lsse += d * d;
                }
            }
        __syncthreads();
        float* red = (float*)smem;
        red[tid] = lsse;
        __syncthreads();
        for (int s = 256; s > 0; s >>= 1) {
            if (tid < s) red[tid] += red[tid + s];
            __syncthreads();
        }
        if (tid == 0) ssePartial[by * nx + bx] = red[0];
    } else if constexpr (EPI == 3) {
        __syncthreads();
        float* sv = (float*)smem;            // [4][256]
        int*   si = (int*)(sv + 1024);
        #pragma unroll
        for (int mt = 0; mt < 4; mt++)
            #pragma unroll
            for (int reg = 0; reg < 16; reg++) {
                float best = INFINITY;
                int bidx = 0x7fffffff;
                #pragma unroll
                for (int nt = 0; nt < 2; nt++) {
                    const int col = n0 + wc * 64 + nt * 32 + c32;
                    float sc = bias[col] - 2.0f * acc[mt][nt][reg];
                    if (sc < best || (sc == best && col < bidx)) { best = sc; bidx = col; }
                }
                #pragma unroll
                for (int d = 1; d < 32; d <<= 1) {
                    float ov = __shfl_xor(best, d, 64);
                    int   oi = __shfl_xor(bidx, d, 64);
                    if (ov < best || (ov == best && oi < bidx)) { best = ov; bidx = oi; }
                }
                if (c32 == 0) {
                    const int rl = wr * 128 + mt * 32 +
                                   (reg & 3) + 8 * (reg >> 2) + 4 * half;
                    sv[wc * 256 + rl] = best;
                    si[wc * 256 + rl] = bidx;
                }
            }
        __syncthreads();
        if (tid < 256) {
            float v0 = sv[tid];
            int   i0 = si[tid];
            #pragma unroll
            for (int c = 1; c < 4; c++) {
                float v1 = sv[c * 256 + tid];
                int   i1 = si[c * 256 + tid];
                if (v1 < v0 || (v1 == v0 && i1 < i0)) { v0 = v1; i0 = i1; }
            }
            pval[(size_t)(m0 + tid) * nx + bx] = v0;
            pidx[(size_t)(m0 + tid) * nx + bx] = i0;
        }
    }
}

// ---------------------------------------------------------------------------
// enc3 GEMM (r7-proven, unchanged): 128x128 tile, 16x16x32 MFMA, waves 2x4,
// 3 buffers, distance-2 prefetch, counted vmcnt(4). SPLIT in, PACKOUT out.
__global__ __launch_bounds__(512, 2)
void gemm_enc3(const ushort* __restrict__ A, const ushort* __restrict__ B,
               const float* __restrict__ bias, int Kd, int Nn,
               int rsA, int rsB, ushort* __restrict__ Cu)
{
    extern __shared__ ushort smem[];
    constexpr int BUFS = 256 * 64;                  // 32KB per buffer

    const int tid = threadIdx.x;
    const int wave = tid >> 6, lane = tid & 63;

    const int nx = gridDim.x;
    const int nwg = nx * gridDim.y;
    const int orig = blockIdx.y * nx + blockIdx.x;
    const int wgid = (orig & 7) * (nwg >> 3) + (orig >> 3);
    const int bx = wgid % nx, by = wgid / nx;

    const int m0 = by * 128, n0 = bx * 128;
    const int wr = wave >> 2, wc = wave & 3;
    const int fcol = lane & 15, kgrp = lane >> 4;
    const int NT = Kd / 32;

    const int srow = lane >> 3;
    const int sswz = ((lane & 7) ^ srow) << 4;
    const char* Abase = (const char*)A + (size_t)m0 * rsA;
    const char* Bbase = (const char*)B + (size_t)n0 * rsB;

    f32x4 acc[4][2];
    #pragma unroll
    for (int m = 0; m < 4; m++)
        #pragma unroll
        for (int n = 0; n < 2; n++)
            acc[m][n] = (f32x4){0.f, 0.f, 0.f, 0.f};

    auto STAGE = [&](int buf, int t) {
        ushort* dst = smem + buf * BUFS;
        const size_t kb = (size_t)t * 128;
        #pragma unroll
        for (int g = 0; g < 2; g++) {
            const int rb = g * 64 + wave * 8;
            gload16(Abase + (size_t)(rb + srow) * rsA + kb + sswz, dst + rb * 64);
            gload16(Bbase + (size_t)(rb + srow) * rsB + kb + sswz,
                    dst + (128 + rb) * 64);
        }
    };
    auto LD = [&](int buf, int r, int u) -> s16x8 {
        return *(const s16x8*)(smem + buf * BUFS + r * 64 + ((u ^ (r & 7)) << 3));
    };

    STAGE(0, 0);
    STAGE(1, 1);
    for (int t = 0; t < NT; ++t) {
        if (t + 1 < NT) asm volatile("s_waitcnt vmcnt(4)" ::: "memory");
        else            asm volatile("s_waitcnt vmcnt(0)" ::: "memory");
        __builtin_amdgcn_s_barrier();
        if (t + 2 < NT) STAGE((t + 2) % 3, t + 2);
        const int buf = t % 3;
        s16x8 aH[4], aL[4], bH[2], bL[2];
        #pragma unroll
        for (int m = 0; m < 4; m++) {
            const int r = wr * 64 + m * 16 + fcol;
            aH[m] = LD(buf, r, kgrp);
            aL[m] = LD(buf, r, 4 + kgrp);
        }
        #pragma unroll
        for (int n = 0; n < 2; n++) {
            const int r = 128 + wc * 32 + n * 16 + fcol;
            bH[n] = LD(buf, r, kgrp);
            bL[n] = LD(buf, r, 4 + kgrp);
        }
        __builtin_amdgcn_s_setprio(1);
        #pragma unroll
        for (int m = 0; m < 4; m++)
            #pragma unroll
            for (int n = 0; n < 2; n++) {
                acc[m][n] = __builtin_amdgcn_mfma_f32_16x16x32_bf16(aH[m], bH[n], acc[m][n], 0, 0, 0);
                acc[m][n] = __builtin_amdgcn_mfma_f32_16x16x32_bf16(aH[m], bL[n], acc[m][n], 0, 0, 0);
                acc[m][n] = __builtin_amdgcn_mfma_f32_16x16x32_bf16(aL[m], bH[n], acc[m][n], 0, 0, 0);
            }
        __builtin_amdgcn_s_setprio(0);
    }
    __builtin_amdgcn_sched_barrier(0);

    #pragma unroll
    for (int n = 0; n < 2; n++) {
        const int col = n0 + wc * 32 + n * 16 + fcol;
        const float bc = bias[col];
        #pragma unroll
        for (int m = 0; m < 4; m++)
            #pragma unroll
            for (int v = 0; v < 4; v++) {
                const int row = m0 + wr * 64 + m * 16 + kgrp * 4 + v;
                float val = acc[m][n][v] + bc;
                size_t o = (size_t)row * 2 * Nn + ((col >> 5) << 6) + (col & 31);
                ushort h = f2bf(val);
                Cu[o] = h;
                Cu[o + 32] = f2bf(val - bf2f(h));
            }
    }
}

// ---------------------------------------------------------------------------
// 4 rows per block: reduce nblk block partials -> kbest; one-hot (nontemporal);
// gather z_q; VQ partial.
__global__ __launch_bounds__(256)
void argmin_final(const float* __restrict__ pval, const int* __restrict__ pidx,
                  int nblk, const ushort* __restrict__ zEp,
                  const float* __restrict__ pool,
                  float* __restrict__ zdisc, ushort* __restrict__ zq,
                  float* __restrict__ vqP)
{
    const int t = threadIdx.x;
    const int r = blockIdx.x * 4 + (t >> 6);
    const int l = t & 63;

    float best = INFINITY;
    int bi = 0x7fffffff;
    if (l < nblk) {
        best = pval[(size_t)r * nblk + l];
        bi = pidx[(size_t)r * nblk + l];
    }
    #pragma unroll
    for (int d = 32; d > 0; d >>= 1) {
        float ov = __shfl_xor(best, d, 64);
        int   oi = __shfl_xor(bi, d, 64);
        if (ov < best || (ov == best && oi < bi)) { best = ov; bi = oi; }
    }
    const int kbest = bi;

    f32x4* zrow = (f32x4*)(zdisc + (size_t)r * 4096);
    #pragma unroll
    for (int it = 0; it < 16; it++) {
        const int j = it * 64 + l;
        f32x4 o = (f32x4){0.f, 0.f, 0.f, 0.f};
        if ((kbest >> 2) == j) o[kbest & 3] = 1.0f;
        __builtin_nontemporal_store(o, &zrow[j]);
    }

    const float4 pz = *(const float4*)(pool + (size_t)kbest * 256 + l * 4);
    *(ushort4*)(zq + (size_t)r * 256 + l * 4) =
        make_ushort4(f2bf(pz.x), f2bf(pz.y), f2bf(pz.z), f2bf(pz.w));
    const size_t zo = (size_t)r * 512 + (((l * 4) >> 5) << 6) + ((l * 4) & 31);
    const ushort4 zh = *(const ushort4*)(zEp + zo);
    const ushort4 zl = *(const ushort4*)(zEp + zo + 32);
    float d0 = bf2f(zh.x) + bf2f(zl.x) - pz.x;
    float d1 = bf2f(zh.y) + bf2f(zl.y) - pz.y;
    float d2 = bf2f(zh.z) + bf2f(zl.z) - pz.z;
    float d3 = bf2f(zh.w) + bf2f(zl.w) - pz.w;
    float s = d0 * d0 + d1 * d1 + d2 * d2 + d3 * d3;
    #pragma unroll
    for (int o = 32; o > 0; o >>= 1) s += __shfl_xor(s, o, 64);
    if (l == 0) vqP[r] = s;
}

__global__ __launch_bounds__(256)
void loss_final(const float* __restrict__ sseP, int nP,
                const float* __restrict__ vqP, int nV,
                float* __restrict__ out)
{
    int tid = threadIdx.x;
    float sx = 0.0f, svq = 0.0f;
    for (int i = tid; i < nP; i += 256) sx += sseP[i];
    for (int i = tid; i < nV; i += 256) svq += vqP[i];
    __shared__ float a[256], b[256];
    a[tid] = sx; b[tid] = svq;
    __syncthreads();
    for (int s = 128; s > 0; s >>= 1) {
        if (tid < s) { a[tid] += a[tid + s]; b[tid] += b[tid + s]; }
        __syncthreads();
    }
    if (tid == 0) out[0] = (a[0] + 1.25f * b[0]) / 16384.0f;
}

// ---------------------------------------------------------------------------
extern "C" void kernel_launch(void* const* d_in, const int* in_sizes, int n_in,
                              void* d_out, int out_size, void* d_ws, size_t ws_size,
                              hipStream_t stream)
{
    const float* x    = (const float*)d_in[0];
    const float* pool = (const float*)d_in[1];
    const float* ew1  = (const float*)d_in[2];
    const float* eb1  = (const float*)d_in[3];
    const float* ew2  = (const float*)d_in[4];
    const float* eb2  = (const float*)d_in[5];
    const float* ew3  = (const float*)d_in[6];
    const float* eb3  = (const float*)d_in[7];
    const float* dw1  = (const float*)d_in[8];
    const float* db1  = (const float*)d_in[9];
    const float* dw2  = (const float*)d_in[10];
    const float* db2  = (const float*)d_in[11];
    const float* dw3  = (const float*)d_in[12];
    const float* db3  = (const float*)d_in[13];

    const int N = 16384, D = 1024, H = 1024, L = 256, K = 4096;

    float* out   = (float*)d_out;
    float* xpred = out;
    float* zdisc = out + (size_t)N * D;
    float* lossp = zdisc + (size_t)N * K;

    char* ws = (char*)d_ws;
    ushort* xp    = (ushort*)(ws + 0 * MB);    // 64MB packed x
    ushort* h1p   = (ushort*)(ws + 64 * MB);   // 64MB
    ushort* h2p   = (ushort*)(ws + 128 * MB);  // 64MB
    ushort* zEp   = (ushort*)(ws + 192 * MB);  // 16MB
    ushort* zq    = (ushort*)(ws + 208 * MB);  // 8MB plain bf16
    ushort* poolp = (ushort*)(ws + 216 * MB);  // 4MB
    ushort* w1p   = (ushort*)(ws + 220 * MB);  // 4MB
    ushort* w2p   = (ushort*)(ws + 224 * MB);  // 4MB
    ushort* w3p   = (ushort*)(ws + 228 * MB);  // 1MB
    ushort* v1    = (ushort*)(ws + 229 * MB);  // 0.5MB plain
    ushort* v2    = (ushort*)(ws + 230 * MB);  // 2MB
    ushort* v3    = (ushort*)(ws + 232 * MB);  // 2MB
    ushort* h3    = (ushort*)(ws + 240 * MB);  // 32MB plain
    ushort* h4    = (ushort*)(ws + 272 * MB);  // 32MB
    float*  cn    = (float*)(ws + 304 * MB);   // 16KB
    float*  pv    = (float*)(ws + 305 * MB);   // 1MB
    int*    pi    = (int*)(ws + 307 * MB);     // 1MB
    float*  vqP   = (float*)(ws + 309 * MB);   // 64KB
    float*  sxP   = (float*)(ws + 310 * MB);   // 4KB

    const int SH_BIG = 2 * (512 * 64) * 2;     // 131072 B
    const int SH_E3  = 3 * (256 * 64) * 2;     // 98304 B
    (void)hipFuncSetAttribute((const void*)gemm_big<1, true, true>,
        hipFuncAttributeMaxDynamicSharedMemorySize, SH_BIG);
    (void)hipFuncSetAttribute((const void*)gemm_big<3, true, false>,
        hipFuncAttributeMaxDynamicSharedMemorySize, SH_BIG);
    (void)hipFuncSetAttribute((const void*)gemm_big<1, false, false>,
        hipFuncAttributeMaxDynamicSharedMemorySize, SH_BIG);
    (void)hipFuncSetAttribute((const void*)gemm_big<2, false, false>,
        hipFuncAttributeMaxDynamicSharedMemorySize, SH_BIG);
    (void)hipFuncSetAttribute((const void*)gemm_enc3,
        hipFuncAttributeMaxDynamicSharedMemorySize, SH_E3);

    dim3 blk(256), gblk(512);

    // prep
    split_pack<<<2048, blk, 0, stream>>>(x, xp, N, D);
    split_pack<<<512, blk, 0, stream>>>(pool, poolp, K, L);
    colnorm<<<K, 64, 0, stream>>>(pool, cn);
    transpose_cvt<true><<<dim3(H / 32, D / 32), blk, 0, stream>>>(ew1, w1p, D, H);
    transpose_cvt<true><<<dim3(H / 32, H / 32), blk, 0, stream>>>(ew2, w2p, H, H);
    transpose_cvt<true><<<dim3(L / 32, H / 32), blk, 0, stream>>>(ew3, w3p, H, L);
    transpose_cvt<false><<<dim3(H / 32, L / 32), blk, 0, stream>>>(dw1, v1, L, H);
    transpose_cvt<false><<<dim3(H / 32, H / 32), blk, 0, stream>>>(dw2, v2, H, H);
    transpose_cvt<false><<<dim3(D / 32, H / 32), blk, 0, stream>>>(dw3, v3, H, D);

    // encoder (split, packed in/out)
    gemm_big<1, true, true><<<dim3(H / 256, N / 256), gblk, SH_BIG, stream>>>(
        xp, w1p, eb1, D, H, 2 * D * 2, 2 * D * 2, h1p, nullptr, nullptr, nullptr, nullptr, nullptr);
    gemm_big<1, true, true><<<dim3(H / 256, N / 256), gblk, SH_BIG, stream>>>(
        h1p, w2p, eb2, H, H, 2 * H * 2, 2 * H * 2, h2p, nullptr, nullptr, nullptr, nullptr, nullptr);
    // enc3: 128-tile kernel -> 256 blocks (full GPU; L=256 cols only)
    gemm_enc3<<<dim3(L / 128, N / 128), gblk, SH_E3, stream>>>(
        h2p, w3p, eb3, H, L, 2 * H * 2, 2 * H * 2, zEp);

    // VQ scores + fused per-block argmin (split)
    gemm_big<3, true, false><<<dim3(K / 256, N / 256), gblk, SH_BIG, stream>>>(
        zEp, poolp, cn, L, K, 2 * L * 2, 2 * L * 2, nullptr, nullptr, nullptr, nullptr, pv, pi);

    argmin_final<<<N / 4, blk, 0, stream>>>(pv, pi, K / 256, zEp, pool, zdisc, zq, vqP);

    // decoder (plain bf16)
    gemm_big<1, false, false><<<dim3(H / 256, N / 256), gblk, SH_BIG, stream>>>(
        zq, v1, db1, L, H, L * 2, L * 2, h3, nullptr, nullptr, nullptr, nullptr, nullptr);
    gemm_big<1, false, false><<<dim3(H / 256, N / 256), gblk, SH_BIG, stream>>>(
        h3, v2, db2, H, H, H * 2, H * 2, h4, nullptr, nullptr, nullptr, nullptr, nullptr);
    gemm_big<2, false, false><<<dim3(D / 256, N / 256), gblk, SH_BIG, stream>>>(
        h4, v3, db3, H, D, H * 2, H * 2, nullptr, xpred, x, sxP, nullptr, nullptr);

    loss_final<<<1, blk, 0, stream>>>(sxP, (D / 256) * (N / 256), vqP, N, lossp);
}

// Round 10
// 581.869 us; speedup vs baseline: 1.3794x; 1.2142x over previous
//
#include <hip/hip_runtime.h>
#include <math.h>

// MinVQVAE1D forward. r7 GEMM structure (256x256 tile, 16x16x32 MFMA,
// 128x64/wave, 2-buffer, scatter epilogues) + single merged prep kernel.
// N=16384, D=1024, H=1024, L=256, K=4096.
// out = [x_pred (N*D) f32 | z_discrete 0/1 f32 (N*K) | loss (1)]

#define MB (1024ULL * 1024ULL)

typedef __attribute__((ext_vector_type(8))) short s16x8;
typedef __attribute__((ext_vector_type(4))) float f32x4;

__device__ __forceinline__ ushort f2bf(float f) {
    unsigned u = __float_as_uint(f);
    u += 0x7fffu + ((u >> 16) & 1u);
    return (ushort)(u >> 16);
}
__device__ __forceinline__ float bf2f(ushort h) {
    return __uint_as_float(((unsigned)h) << 16);
}
__device__ __forceinline__ float gelu_f(float v) {
    return 0.5f * v * (1.0f + erff(v * 0.70710678118654752f));
}
__device__ __forceinline__ void gload16(const void* g, void* l) {
    __builtin_amdgcn_global_load_lds(
        (const __attribute__((address_space(1))) void*)g,
        (__attribute__((address_space(3))) void*)l, 16, 0, 0);
}

// ---------------------------------------------------------------------------
// Merged prep: x hilo-pack | pool hilo-pack | colnorm | 6 weight transposes.
// 8192 blocks x 256 threads, segment dispatch by blockIdx.x.
__device__ __forceinline__ void split_body(const float* __restrict__ in,
                                           ushort* __restrict__ out,
                                           int K, int nch, int vb, int nB)
{
    for (int i = vb * 256 + threadIdx.x; i < nch; i += nB * 256) {
        const int row = i / (K >> 3);
        const int k8 = (i - row * (K >> 3)) * 8;
        const float4 v0 = *(const float4*)(in + (size_t)row * K + k8);
        const float4 v1 = *(const float4*)(in + (size_t)row * K + k8 + 4);
        float f[8] = {v0.x, v0.y, v0.z, v0.w, v1.x, v1.y, v1.z, v1.w};
        ushort h[8], l[8];
        #pragma unroll
        for (int j = 0; j < 8; j++) {
            h[j] = f2bf(f[j]);
            l[j] = f2bf(f[j] - bf2f(h[j]));
        }
        size_t o = (size_t)row * 2 * K + ((k8 >> 5) << 6) + (k8 & 31);
        *(ushort4*)(out + o)      = make_ushort4(h[0], h[1], h[2], h[3]);
        *(ushort4*)(out + o + 4)  = make_ushort4(h[4], h[5], h[6], h[7]);
        *(ushort4*)(out + o + 32) = make_ushort4(l[0], l[1], l[2], l[3]);
        *(ushort4*)(out + o + 36) = make_ushort4(l[4], l[5], l[6], l[7]);
    }
}

__global__ __launch_bounds__(256)
void prep_all(const float* __restrict__ x, ushort* __restrict__ xp,
              const float* __restrict__ pool, ushort* __restrict__ poolp,
              float* __restrict__ cn,
              const float* __restrict__ ew1, ushort* __restrict__ w1p,
              const float* __restrict__ ew2, ushort* __restrict__ w2p,
              const float* __restrict__ ew3, ushort* __restrict__ w3p,
              const float* __restrict__ dw1, ushort* __restrict__ v1,
              const float* __restrict__ dw2, ushort* __restrict__ v2,
              const float* __restrict__ dw3, ushort* __restrict__ v3)
{
    __shared__ float tile[32][33];
    const int b = blockIdx.x;
    const int tid = threadIdx.x;

    if (b < 2048) {
        split_body(x, xp, 1024, 16384 * (1024 / 8), b, 2048);
        return;
    }
    if (b < 2560) {
        split_body(pool, poolp, 256, 4096 * (256 / 8), b - 2048, 512);
        return;
    }
    if (b < 3584) {
        // colnorm: 4 rows per block (one wave each)
        const int r = (b - 2560) * 4 + (tid >> 6);
        const int lane = tid & 63;
        float4 v = *(const float4*)(pool + (size_t)r * 256 + lane * 4);
        float s = v.x * v.x + v.y * v.y + v.z * v.z + v.w * v.w;
        #pragma unroll
        for (int o = 32; o > 0; o >>= 1) s += __shfl_down(s, o);
        if (lane == 0) cn[r] = s;
        return;
    }

    const float* in; ushort* out; int Kd, Nn, vb; bool pack;
    if (b < 4608)      { in = ew1; out = w1p; Kd = 1024; Nn = 1024; vb = b - 3584; pack = true; }
    else if (b < 5632) { in = ew2; out = w2p; Kd = 1024; Nn = 1024; vb = b - 4608; pack = true; }
    else if (b < 5888) { in = ew3; out = w3p; Kd = 1024; Nn = 256;  vb = b - 5632; pack = true; }
    else if (b < 6144) { in = dw1; out = v1;  Kd = 256;  Nn = 1024; vb = b - 5888; pack = false; }
    else if (b < 7168) { in = dw2; out = v2;  Kd = 1024; Nn = 1024; vb = b - 6144; pack = false; }
    else               { in = dw3; out = v3;  Kd = 1024; Nn = 1024; vb = b - 7168; pack = false; }

    const int nxw = Nn / 32;
    const int n0 = (vb % nxw) * 32, k0 = (vb / nxw) * 32;
    const int tx = tid & 31, ty = tid >> 5;
    #pragma unroll
    for (int r = 0; r < 4; r++)
        tile[ty + r * 8][tx] = in[(size_t)(k0 + ty + r * 8) * Nn + n0 + tx];
    __syncthreads();
    #pragma unroll
    for (int r = 0; r < 4; r++) {
        const float v = tile[tx][ty + r * 8];
        const int row = n0 + ty + r * 8, k = k0 + tx;
        if (pack) {
            size_t o = (size_t)row * 2 * Kd + ((k >> 5) << 6) + (k & 31);
            ushort h = f2bf(v);
            out[o] = h;
            out[o + 32] = f2bf(v - bf2f(h));
        } else {
            out[(size_t)row * Kd + k] = f2bf(v);
        }
    }
}

// ---------------------------------------------------------------------------
// Big MFMA GEMM (r7-proven): C[M,Nn] = A[M,Kd] @ B^T, B given as [Nn,Kd].
// Block tile 256x256, 512 threads = 8 waves (2x4), per-wave 128x64 output.
// 2 LDS buffers x 64KB, depth-1 prefetch: vmcnt(0) -> barrier -> STAGE(t+1)
// -> compute(t). XCD-bijective block swizzle. Scatter epilogues.
// SPLIT: BK=32 hilo slab (3 MFMA/frag pair); plain: BK=64.
// EPI: 0=+bias, 1=gelu(+bias), 2=sigmoid(+bias)+SSE, 3=VQ argmin partials.
template<int EPI, bool SPLIT, bool PACKOUT>
__global__ __launch_bounds__(512, 2)
void gemm_big(const ushort* __restrict__ A, const ushort* __restrict__ B,
              const float* __restrict__ bias, int Kd, int Nn,
              int rsA, int rsB,                    // row strides in BYTES
              ushort* __restrict__ Cu, float* __restrict__ Cf,
              const float* __restrict__ xref, float* __restrict__ ssePartial,
              float* __restrict__ pval, int* __restrict__ pidx)
{
    extern __shared__ ushort smem[];
    constexpr int BUFS = 512 * 64;                  // 64KB per buffer

    const int tid = threadIdx.x;
    const int wave = tid >> 6, lane = tid & 63;

    const int nx = gridDim.x;
    const int nwg = nx * gridDim.y;
    const int orig = blockIdx.y * nx + blockIdx.x;
    const int wgid = (orig & 7) * (nwg >> 3) + (orig >> 3);
    const int bx = wgid % nx, by = wgid / nx;

    const int m0 = by * 256, n0 = bx * 256;
    const int wr = wave >> 2, wc = wave & 3;        // 2 x 4 wave grid
    const int fcol = lane & 15, kgrp = lane >> 4;
    const int NT = Kd / (SPLIT ? 32 : 64);

    const int srow = lane >> 3;                     // row within 8-row chunk
    const int sswz = ((lane & 7) ^ srow) << 4;      // swizzled src byte
    const char* Abase = (const char*)A + (size_t)m0 * rsA;
    const char* Bbase = (const char*)B + (size_t)n0 * rsB;

    f32x4 acc[8][4];
    #pragma unroll
    for (int m = 0; m < 8; m++)
        #pragma unroll
        for (int n = 0; n < 4; n++)
            acc[m][n] = (f32x4){0.f, 0.f, 0.f, 0.f};

    auto STAGE = [&](int buf, int t) {
        ushort* dst = smem + buf * BUFS;
        const size_t kb = (size_t)t * 128;
        #pragma unroll
        for (int g = 0; g < 4; g++) {
            const int rb = g * 64 + wave * 8;
            gload16(Abase + (size_t)(rb + srow) * rsA + kb + sswz, dst + rb * 64);
            gload16(Bbase + (size_t)(rb + srow) * rsB + kb + sswz,
                    dst + (256 + rb) * 64);
        }
    };
    auto LD = [&](int buf, int r, int u) -> s16x8 {
        return *(const s16x8*)(smem + buf * BUFS + r * 64 + ((u ^ (r & 7)) << 3));
    };

    STAGE(0, 0);
    for (int t = 0; t < NT; ++t) {
        asm volatile("s_waitcnt vmcnt(0)" ::: "memory");
        __builtin_amdgcn_s_barrier();
        if (t + 1 < NT) STAGE((t + 1) & 1, t + 1);
        const int buf = t & 1;
        if constexpr (SPLIT) {
            s16x8 bH[4], bL[4];
            #pragma unroll
            for (int n = 0; n < 4; n++) {
                const int r = 256 + wc * 64 + n * 16 + fcol;
                bH[n] = LD(buf, r, kgrp);
                bL[n] = LD(buf, r, 4 + kgrp);
            }
            #pragma unroll
            for (int h = 0; h < 2; h++) {
                s16x8 aH[4], aL[4];
                #pragma unroll
                for (int i = 0; i < 4; i++) {
                    const int r = wr * 128 + (h * 4 + i) * 16 + fcol;
                    aH[i] = LD(buf, r, kgrp);
                    aL[i] = LD(buf, r, 4 + kgrp);
                }
                __builtin_amdgcn_s_setprio(1);
                #pragma unroll
                for (int i = 0; i < 4; i++)
                    #pragma unroll
                    for (int n = 0; n < 4; n++) {
                        acc[h * 4 + i][n] = __builtin_amdgcn_mfma_f32_16x16x32_bf16(
                            aH[i], bH[n], acc[h * 4 + i][n], 0, 0, 0);
                        acc[h * 4 + i][n] = __builtin_amdgcn_mfma_f32_16x16x32_bf16(
                            aH[i], bL[n], acc[h * 4 + i][n], 0, 0, 0);
                        acc[h * 4 + i][n] = __builtin_amdgcn_mfma_f32_16x16x32_bf16(
                            aL[i], bH[n], acc[h * 4 + i][n], 0, 0, 0);
                    }
                __builtin_amdgcn_s_setprio(0);
            }
        } else {
            s16x8 b2[4][2];
            #pragma unroll
            for (int n = 0; n < 4; n++) {
                const int r = 256 + wc * 64 + n * 16 + fcol;
                #pragma unroll
                for (int ks = 0; ks < 2; ks++) b2[n][ks] = LD(buf, r, ks * 4 + kgrp);
            }
            #pragma unroll
            for (int h = 0; h < 2; h++) {
                s16x8 a2[4][2];
                #pragma unroll
                for (int i = 0; i < 4; i++) {
                    const int r = wr * 128 + (h * 4 + i) * 16 + fcol;
                    #pragma unroll
                    for (int ks = 0; ks < 2; ks++) a2[i][ks] = LD(buf, r, ks * 4 + kgrp);
                }
                __builtin_amdgcn_s_setprio(1);
                #pragma unroll
                for (int i = 0; i < 4; i++)
                    #pragma unroll
                    for (int n = 0; n < 4; n++)
                        #pragma unroll
                        for (int ks = 0; ks < 2; ks++)
                            acc[h * 4 + i][n] = __builtin_amdgcn_mfma_f32_16x16x32_bf16(
                                a2[i][ks], b2[n][ks], acc[h * 4 + i][n], 0, 0, 0);
                __builtin_amdgcn_s_setprio(0);
            }
        }
    }
    __builtin_amdgcn_sched_barrier(0);

    // ------------------------------ epilogue ------------------------------
    int colg[4];
    float bcol[4];
    #pragma unroll
    for (int n = 0; n < 4; n++) {
        colg[n] = n0 + wc * 64 + n * 16 + fcol;
        bcol[n] = bias[colg[n]];
    }

    if constexpr (EPI == 0 || EPI == 1) {
        #pragma unroll
        for (int m = 0; m < 8; m++)
            #pragma unroll
            for (int v = 0; v < 4; v++) {
                const int row = m0 + wr * 128 + m * 16 + kgrp * 4 + v;
                #pragma unroll
                for (int n = 0; n < 4; n++) {
                    float val = acc[m][n][v] + bcol[n];
                    if (EPI == 1) val = gelu_f(val);
                    if constexpr (PACKOUT) {
                        size_t o = (size_t)row * 2 * Nn + ((colg[n] >> 5) << 6) + (colg[n] & 31);
                        ushort h = f2bf(val);
                        Cu[o] = h;
                        Cu[o + 32] = f2bf(val - bf2f(h));
                    } else {
                        Cu[(size_t)row * Nn + colg[n]] = f2bf(val);
                    }
                }
            }
    } else if constexpr (EPI == 2) {
        float lsse = 0.0f;
        #pragma unroll
        for (int m = 0; m < 8; m++)
            #pragma unroll
            for (int v = 0; v < 4; v++) {
                const int row = m0 + wr * 128 + m * 16 + kgrp * 4 + v;
                const size_t rb = (size_t)row * Nn;
                #pragma unroll
                for (int n = 0; n < 4; n++) {
                    float val = acc[m][n][v] + bcol[n];
                    val = 1.0f / (1.0f + expf(-val));
                    __builtin_nontemporal_store(val, &Cf[rb + colg[n]]);
                    float d = xref[rb + colg[n]] - val;
                    lsse += d * d;
                }
            }
        __syncthreads();
        float* red = (float*)smem;
        red[tid] = lsse;
        __syncthreads();
        for (int s = 256; s > 0; s >>= 1) {
            if (tid < s) red[tid] += red[tid + s];
            __syncthreads();
        }
        if (tid == 0) ssePartial[by * nx + bx] = red[0];
    } else if constexpr (EPI == 3) {
        __syncthreads();
        float* sv = (float*)smem;            // [4][256]
        int*   si = (int*)(sv + 1024);
        #pragma unroll
        for (int m = 0; m < 8; m++)
            #pragma unroll
            for (int v = 0; v < 4; v++) {
                float best = INFINITY;
                int bidx = 0x7fffffff;
                #pragma unroll
                for (int n = 0; n < 4; n++) {
                    float sc = bcol[n] - 2.0f * acc[m][n][v];
                    if (sc < best || (sc == best && colg[n] < bidx)) { best = sc; bidx = colg[n]; }
                }
                #pragma unroll
                for (int d = 1; d < 16; d <<= 1) {
                    float ov = __shfl_xor(best, d, 64);
                    int   oi = __shfl_xor(bidx, d, 64);
                    if (ov < best || (ov == best && oi < bidx)) { best = ov; bidx = oi; }
                }
                if (fcol == 0) {
                    const int rl = wr * 128 + m * 16 + kgrp * 4 + v;
                    sv[wc * 256 + rl] = best;
                    si[wc * 256 + rl] = bidx;
                }
            }
        __syncthreads();
        if (tid < 256) {
            float v0 = sv[tid];
            int   i0 = si[tid];
            #pragma unroll
            for (int c = 1; c < 4; c++) {
                float v1 = sv[c * 256 + tid];
                int   i1 = si[c * 256 + tid];
                if (v1 < v0 || (v1 == v0 && i1 < i0)) { v0 = v1; i0 = i1; }
            }
            pval[(size_t)(m0 + tid) * nx + bx] = v0;
            pidx[(size_t)(m0 + tid) * nx + bx] = i0;
        }
    }
}

// ---------------------------------------------------------------------------
// enc3 GEMM (r7-proven): 128x128 tile, waves 2x4 (64x32/wave), 3 buffers,
// distance-2 prefetch, counted vmcnt(4). SPLIT in, PACKOUT out.
__global__ __launch_bounds__(512, 2)
void gemm_enc3(const ushort* __restrict__ A, const ushort* __restrict__ B,
               const float* __restrict__ bias, int Kd, int Nn,
               int rsA, int rsB, ushort* __restrict__ Cu)
{
    extern __shared__ ushort smem[];
    constexpr int BUFS = 256 * 64;                  // 32KB per buffer

    const int tid = threadIdx.x;
    const int wave = tid >> 6, lane = tid & 63;

    const int nx = gridDim.x;
    const int nwg = nx * gridDim.y;
    const int orig = blockIdx.y * nx + blockIdx.x;
    const int wgid = (orig & 7) * (nwg >> 3) + (orig >> 3);
    const int bx = wgid % nx, by = wgid / nx;

    const int m0 = by * 128, n0 = bx * 128;
    const int wr = wave >> 2, wc = wave & 3;
    const int fcol = lane & 15, kgrp = lane >> 4;
    const int NT = Kd / 32;

    const int srow = lane >> 3;
    const int sswz = ((lane & 7) ^ srow) << 4;
    const char* Abase = (const char*)A + (size_t)m0 * rsA;
    const char* Bbase = (const char*)B + (size_t)n0 * rsB;

    f32x4 acc[4][2];
    #pragma unroll
    for (int m = 0; m < 4; m++)
        #pragma unroll
        for (int n = 0; n < 2; n++)
            acc[m][n] = (f32x4){0.f, 0.f, 0.f, 0.f};

    auto STAGE = [&](int buf, int t) {
        ushort* dst = smem + buf * BUFS;
        const size_t kb = (size_t)t * 128;
        #pragma unroll
        for (int g = 0; g < 2; g++) {
            const int rb = g * 64 + wave * 8;
            gload16(Abase + (size_t)(rb + srow) * rsA + kb + sswz, dst + rb * 64);
            gload16(Bbase + (size_t)(rb + srow) * rsB + kb + sswz,
                    dst + (128 + rb) * 64);
        }
    };
    auto LD = [&](int buf, int r, int u) -> s16x8 {
        return *(const s16x8*)(smem + buf * BUFS + r * 64 + ((u ^ (r & 7)) << 3));
    };

    STAGE(0, 0);
    STAGE(1, 1);
    for (int t = 0; t < NT; ++t) {
        if (t + 1 < NT) asm volatile("s_waitcnt vmcnt(4)" ::: "memory");
        else            asm volatile("s_waitcnt vmcnt(0)" ::: "memory");
        __builtin_amdgcn_s_barrier();
        if (t + 2 < NT) STAGE((t + 2) % 3, t + 2);
        const int buf = t % 3;
        s16x8 aH[4], aL[4], bH[2], bL[2];
        #pragma unroll
        for (int m = 0; m < 4; m++) {
            const int r = wr * 64 + m * 16 + fcol;
            aH[m] = LD(buf, r, kgrp);
            aL[m] = LD(buf, r, 4 + kgrp);
        }
        #pragma unroll
        for (int n = 0; n < 2; n++) {
            const int r = 128 + wc * 32 + n * 16 + fcol;
            bH[n] = LD(buf, r, kgrp);
            bL[n] = LD(buf, r, 4 + kgrp);
        }
        __builtin_amdgcn_s_setprio(1);
        #pragma unroll
        for (int m = 0; m < 4; m++)
            #pragma unroll
            for (int n = 0; n < 2; n++) {
                acc[m][n] = __builtin_amdgcn_mfma_f32_16x16x32_bf16(aH[m], bH[n], acc[m][n], 0, 0, 0);
                acc[m][n] = __builtin_amdgcn_mfma_f32_16x16x32_bf16(aH[m], bL[n], acc[m][n], 0, 0, 0);
                acc[m][n] = __builtin_amdgcn_mfma_f32_16x16x32_bf16(aL[m], bH[n], acc[m][n], 0, 0, 0);
            }
        __builtin_amdgcn_s_setprio(0);
    }
    __builtin_amdgcn_sched_barrier(0);

    #pragma unroll
    for (int n = 0; n < 2; n++) {
        const int col = n0 + wc * 32 + n * 16 + fcol;
        const float bc = bias[col];
        #pragma unroll
        for (int m = 0; m < 4; m++)
            #pragma unroll
            for (int v = 0; v < 4; v++) {
                const int row = m0 + wr * 64 + m * 16 + kgrp * 4 + v;
                float val = acc[m][n][v] + bc;
                size_t o = (size_t)row * 2 * Nn + ((col >> 5) << 6) + (col & 31);
                ushort h = f2bf(val);
                Cu[o] = h;
                Cu[o + 32] = f2bf(val - bf2f(h));
            }
    }
}

// ---------------------------------------------------------------------------
// 4 rows per block: reduce nblk block partials -> kbest; one-hot (nontemporal);
// gather z_q; VQ partial.
__global__ __launch_bounds__(256)
void argmin_final(const float* __restrict__ pval, const int* __restrict__ pidx,
                  int nblk, const ushort* __restrict__ zEp,
                  const float* __restrict__ pool,
                  float* __restrict__ zdisc, ushort* __restrict__ zq,
                  float* __restrict__ vqP)
{
    const int t = threadIdx.x;
    const int r = blockIdx.x * 4 + (t >> 6);
    const int l = t & 63;

    float best = INFINITY;
    int bi = 0x7fffffff;
    if (l < nblk) {
        best = pval[(size_t)r * nblk + l];
        bi = pidx[(size_t)r * nblk + l];
    }
    #pragma unroll
    for (int d = 32; d > 0; d >>= 1) {
        float ov = __shfl_xor(best, d, 64);
        int   oi = __shfl_xor(bi, d, 64);
        if (ov < best || (ov == best && oi < bi)) { best = ov; bi = oi; }
    }
    const int kbest = bi;

    f32x4* zrow = (f32x4*)(zdisc + (size_t)r * 4096);
    #pragma unroll
    for (int it = 0; it < 16; it++) {
        const int j = it * 64 + l;
        f32x4 o = (f32x4){0.f, 0.f, 0.f, 0.f};
        if ((kbest >> 2) == j) o[kbest & 3] = 1.0f;
        __builtin_nontemporal_store(o, &zrow[j]);
    }

    const float4 pz = *(const float4*)(pool + (size_t)kbest * 256 + l * 4);
    *(ushort4*)(zq + (size_t)r * 256 + l * 4) =
        make_ushort4(f2bf(pz.x), f2bf(pz.y), f2bf(pz.z), f2bf(pz.w));
    const size_t zo = (size_t)r * 512 + (((l * 4) >> 5) << 6) + ((l * 4) & 31);
    const ushort4 zh = *(const ushort4*)(zEp + zo);
    const ushort4 zl = *(const ushort4*)(zEp + zo + 32);
    float d0 = bf2f(zh.x) + bf2f(zl.x) - pz.x;
    float d1 = bf2f(zh.y) + bf2f(zl.y) - pz.y;
    float d2 = bf2f(zh.z) + bf2f(zl.z) - pz.z;
    float d3 = bf2f(zh.w) + bf2f(zl.w) - pz.w;
    float s = d0 * d0 + d1 * d1 + d2 * d2 + d3 * d3;
    #pragma unroll
    for (int o = 32; o > 0; o >>= 1) s += __shfl_xor(s, o, 64);
    if (l == 0) vqP[r] = s;
}

__global__ __launch_bounds__(256)
void loss_final(const float* __restrict__ sseP, int nP,
                const float* __restrict__ vqP, int nV,
                float* __restrict__ out)
{
    int tid = threadIdx.x;
    float sx = 0.0f, svq = 0.0f;
    for (int i = tid; i < nP; i += 256) sx += sseP[i];
    for (int i = tid; i < nV; i += 256) svq += vqP[i];
    __shared__ float a[256], b[256];
    a[tid] = sx; b[tid] = svq;
    __syncthreads();
    for (int s = 128; s > 0; s >>= 1) {
        if (tid < s) { a[tid] += a[tid + s]; b[tid] += b[tid + s]; }
        __syncthreads();
    }
    if (tid == 0) out[0] = (a[0] + 1.25f * b[0]) / 16384.0f;
}

// ---------------------------------------------------------------------------
extern "C" void kernel_launch(void* const* d_in, const int* in_sizes, int n_in,
                              void* d_out, int out_size, void* d_ws, size_t ws_size,
                              hipStream_t stream)
{
    const float* x    = (const float*)d_in[0];
    const float* pool = (const float*)d_in[1];
    const float* ew1  = (const float*)d_in[2];
    const float* eb1  = (const float*)d_in[3];
    const float* ew2  = (const float*)d_in[4];
    const float* eb2  = (const float*)d_in[5];
    const float* ew3  = (const float*)d_in[6];
    const float* eb3  = (const float*)d_in[7];
    const float* dw1  = (const float*)d_in[8];
    const float* db1  = (const float*)d_in[9];
    const float* dw2  = (const float*)d_in[10];
    const float* db2  = (const float*)d_in[11];
    const float* dw3  = (const float*)d_in[12];
    const float* db3  = (const float*)d_in[13];

    const int N = 16384, D = 1024, H = 1024, L = 256, K = 4096;

    float* out   = (float*)d_out;
    float* xpred = out;
    float* zdisc = out + (size_t)N * D;
    float* lossp = zdisc + (size_t)N * K;

    char* ws = (char*)d_ws;
    ushort* xp    = (ushort*)(ws + 0 * MB);    // 64MB packed x
    ushort* h1p   = (ushort*)(ws + 64 * MB);   // 64MB
    ushort* h2p   = (ushort*)(ws + 128 * MB);  // 64MB
    ushort* zEp   = (ushort*)(ws + 192 * MB);  // 16MB
    ushort* zq    = (ushort*)(ws + 208 * MB);  // 8MB plain bf16
    ushort* poolp = (ushort*)(ws + 216 * MB);  // 4MB
    ushort* w1p   = (ushort*)(ws + 220 * MB);  // 4MB
    ushort* w2p   = (ushort*)(ws + 224 * MB);  // 4MB
    ushort* w3p   = (ushort*)(ws + 228 * MB);  // 1MB
    ushort* v1    = (ushort*)(ws + 229 * MB);  // 0.5MB plain
    ushort* v2    = (ushort*)(ws + 230 * MB);  // 2MB
    ushort* v3    = (ushort*)(ws + 232 * MB);  // 2MB
    ushort* h3    = (ushort*)(ws + 240 * MB);  // 32MB plain
    ushort* h4    = (ushort*)(ws + 272 * MB);  // 32MB
    float*  cn    = (float*)(ws + 304 * MB);   // 16KB
    float*  pv    = (float*)(ws + 305 * MB);   // 1MB
    int*    pi    = (int*)(ws + 307 * MB);     // 1MB
    float*  vqP   = (float*)(ws + 309 * MB);   // 64KB
    float*  sxP   = (float*)(ws + 310 * MB);   // 4KB

    const int SH_BIG = 2 * (512 * 64) * 2;     // 131072 B
    const int SH_E3  = 3 * (256 * 64) * 2;     // 98304 B
    (void)hipFuncSetAttribute((const void*)gemm_big<1, true, true>,
        hipFuncAttributeMaxDynamicSharedMemorySize, SH_BIG);
    (void)hipFuncSetAttribute((const void*)gemm_big<3, true, false>,
        hipFuncAttributeMaxDynamicSharedMemorySize, SH_BIG);
    (void)hipFuncSetAttribute((const void*)gemm_big<1, false, false>,
        hipFuncAttributeMaxDynamicSharedMemorySize, SH_BIG);
    (void)hipFuncSetAttribute((const void*)gemm_big<2, false, false>,
        hipFuncAttributeMaxDynamicSharedMemorySize, SH_BIG);
    (void)hipFuncSetAttribute((const void*)gemm_enc3,
        hipFuncAttributeMaxDynamicSharedMemorySize, SH_E3);

    dim3 blk(256), gblk(512);

    // merged prep (x/pool hilo-pack, colnorm, 6 weight transposes)
    prep_all<<<8192, blk, 0, stream>>>(x, xp, pool, poolp, cn,
                                       ew1, w1p, ew2, w2p, ew3, w3p,
                                       dw1, v1, dw2, v2, dw3, v3);

    // encoder (split, packed in/out)
    gemm_big<1, true, true><<<dim3(H / 256, N / 256), gblk, SH_BIG, stream>>>(
        xp, w1p, eb1, D, H, 2 * D * 2, 2 * D * 2, h1p, nullptr, nullptr, nullptr, nullptr, nullptr);
    gemm_big<1, true, true><<<dim3(H / 256, N / 256), gblk, SH_BIG, stream>>>(
        h1p, w2p, eb2, H, H, 2 * H * 2, 2 * H * 2, h2p, nullptr, nullptr, nullptr, nullptr, nullptr);
    // enc3: 128-tile kernel -> 256 blocks (full GPU; L=256 cols only)
    gemm_enc3<<<dim3(L / 128, N / 128), gblk, SH_E3, stream>>>(
        h2p, w3p, eb3, H, L, 2 * H * 2, 2 * H * 2, zEp);

    // VQ scores + fused per-block argmin (split)
    gemm_big<3, true, false><<<dim3(K / 256, N / 256), gblk, SH_BIG, stream>>>(
        zEp, poolp, cn, L, K, 2 * L * 2, 2 * L * 2, nullptr, nullptr, nullptr, nullptr, pv, pi);

    argmin_final<<<N / 4, blk, 0, stream>>>(pv, pi, K / 256, zEp, pool, zdisc, zq, vqP);

    // decoder (plain bf16)
    gemm_big<1, false, false><<<dim3(H / 256, N / 256), gblk, SH_BIG, stream>>>(
        zq, v1, db1, L, H, L * 2, L * 2, h3, nullptr, nullptr, nullptr, nullptr, nullptr);
    gemm_big<1, false, false><<<dim3(H / 256, N / 256), gblk, SH_BIG, stream>>>(
        h3, v2, db2, H, H, H * 2, H * 2, h4, nullptr, nullptr, nullptr, nullptr, nullptr);
    gemm_big<2, false, false><<<dim3(D / 256, N / 256), gblk, SH_BIG, stream>>>(
        h4, v3, db3, H, D, H * 2, H * 2, nullptr, xpred, x, sxP, nullptr, nullptr);

    loss_final<<<1, blk, 0, stream>>>(sxP, (D / 256) * (N / 256), vqP, N, lossp);
}